// Round 2
// baseline (373.920 us; speedup 1.0000x reference)
//
#include <hip/hip_runtime.h>

// Rayleigh-Benard tendency kernel, fp32 I/O, fp32 math.
// Layout: state[6][NX][NY][NZ], z contiguous.

namespace {
constexpr int NXc = 256, NYc = 256, NZc = 128;
constexpr int FS = NXc * NYc * NZc;   // field stride
constexpr int XS = NYc * NZc;         // x stride
constexpr int YS = NZc;               // y stride

constexpr float CVc = 717.0f, MUc = 1.8e-5f, KTHc = 0.025f, Gc = 9.8f;
constexpr float Rgas = 1004.0f - 717.0f;  // CP - CV = 287

// DX=1/256, DY=1/256, DZ=1/127 ; all derived constants exact in fp32
constexpr float inv2dx = 128.0f;      // 0.5/DX
constexpr float inv2dy = 128.0f;      // 0.5/DY
constexpr float inv2dz = 63.5f;       // 0.5/DZ
constexpr float invdx2 = 65536.0f;    // 1/DX^2
constexpr float invdy2 = 65536.0f;    // 1/DY^2
constexpr float invdz2 = 16129.0f;    // 1/DZ^2 = 127^2
}

__global__ __launch_bounds__(256) void rb_kernel(const float* __restrict__ s,
                                                 float* __restrict__ o) {
    const int z = threadIdx.x;                    // 0..127 (contiguous, coalesced)
    const int y = blockIdx.x * 2 + threadIdx.y;   // 0..255
    const int x = blockIdx.y;                     // 0..255

    const int xm = (x == 0) ? NXc - 1 : x - 1;
    const int xp = (x == NXc - 1) ? 0 : x + 1;
    const int ym = (y == 0) ? NYc - 1 : y - 1;
    const int yp = (y == NYc - 1) ? 0 : y + 1;

    const int b   = x * XS + y * YS + z;
    const int bxm = xm * XS + y * YS + z;
    const int bxp = xp * XS + y * YS + z;
    const int bym = x * XS + ym * YS + z;
    const int byp = x * XS + yp * YS + z;

    const float* su = s;
    const float* sv = s + FS;
    const float* sw = s + 2 * FS;
    const float* sr = s + 3 * FS;
    const float* st = s + 4 * FS;
    const float* sc = s + 5 * FS;

    // centers (needed at every z, including walls, for dc/drou)
    const float u_c = su[b], v_c = sv[b], w_c = sw[b];
    const float r_c = sr[b], T_c = st[b], c_c = sc[b];

    // x/y neighbors needed for the all-z outputs (drou, dc)
    const float u_xm = su[bxm], u_xp = su[bxp];
    const float r_xm = sr[bxm], r_xp = sr[bxp];
    const float c_xm = sc[bxm], c_xp = sc[bxp];
    const float c_ym = sc[bym], c_yp = sc[byp];

    // drou = -d/dx(rou*u) — x-periodic central, no z dependence
    const float drou = -(r_xp * u_xp - r_xm * u_xm) * inv2dx;

    // dc = -adv(c); only the z-derivative needs one-sided wall stencils
    float dzc;
    if (z == 0) {
        dzc = (-3.0f * c_c + 4.0f * sc[b + 1] - sc[b + 2]) * inv2dz;
    } else if (z == NZc - 1) {
        dzc = (3.0f * c_c - 4.0f * sc[b - 1] + sc[b - 2]) * inv2dz;
    } else {
        dzc = (sc[b + 1] - sc[b - 1]) * inv2dz;
    }
    const float dc = -(u_c * (c_xp - c_xm) * inv2dx +
                       v_c * (c_yp - c_ym) * inv2dy +
                       w_c * dzc);

    float du = 0.0f, dv = 0.0f, dw = 0.0f, dT = 0.0f;

    if (z > 0 && z < NZc - 1) {
        // interior: du, dv, dw, dT are non-zero (walls zeroed by the reference)
        const float u_ym = su[bym], u_yp = su[byp];
        const float u_zm = su[b - 1], u_zp = su[b + 1];
        const float v_xm = sv[bxm], v_xp = sv[bxp];
        const float v_ym = sv[bym], v_yp = sv[byp];
        const float v_zm = sv[b - 1], v_zp = sv[b + 1];
        const float w_xm = sw[bxm], w_xp = sw[bxp];
        const float w_ym = sw[bym], w_yp = sw[byp];
        const float w_zm = sw[b - 1], w_zp = sw[b + 1];
        const float T_xm = st[bxm], T_xp = st[bxp];
        const float T_ym = st[bym], T_yp = st[byp];
        const float T_zm = st[b - 1], T_zp = st[b + 1];
        const float r_ym = sr[bym], r_yp = sr[byp];
        const float r_zm = sr[b - 1], r_zp = sr[b + 1];

        const float inv_r = 1.0f / r_c;

        // pressure at neighbor points: p = R * rou * T
        const float p_xm = Rgas * r_xm * T_xm, p_xp = Rgas * r_xp * T_xp;
        const float p_ym = Rgas * r_ym * T_ym, p_yp = Rgas * r_yp * T_yp;
        const float p_zm = Rgas * r_zm * T_zm, p_zp = Rgas * r_zp * T_zp;

        const float dpdx = (p_xp - p_xm) * inv2dx;
        const float dpdy = (p_yp - p_ym) * inv2dy;
        const float dpdz = (p_zp - p_zm) * inv2dz;

        const float lap_u = (u_xp + u_xm - 2.0f * u_c) * invdx2 +
                            (u_yp + u_ym - 2.0f * u_c) * invdy2 +
                            (u_zp + u_zm - 2.0f * u_c) * invdz2;
        const float lap_v = (v_xp + v_xm - 2.0f * v_c) * invdx2 +
                            (v_yp + v_ym - 2.0f * v_c) * invdy2 +
                            (v_zp + v_zm - 2.0f * v_c) * invdz2;
        const float lap_w = (w_xp + w_xm - 2.0f * w_c) * invdx2 +
                            (w_yp + w_ym - 2.0f * w_c) * invdy2 +
                            (w_zp + w_zm - 2.0f * w_c) * invdz2;
        const float lap_T = (T_xp + T_xm - 2.0f * T_c) * invdx2 +
                            (T_yp + T_ym - 2.0f * T_c) * invdy2 +
                            (T_zp + T_zm - 2.0f * T_c) * invdz2;

        const float adv_u = u_c * (u_xp - u_xm) * inv2dx +
                            v_c * (u_yp - u_ym) * inv2dy +
                            w_c * (u_zp - u_zm) * inv2dz;
        const float adv_v = u_c * (v_xp - v_xm) * inv2dx +
                            v_c * (v_yp - v_ym) * inv2dy +
                            w_c * (v_zp - v_zm) * inv2dz;
        const float adv_w = u_c * (w_xp - w_xm) * inv2dx +
                            v_c * (w_yp - w_ym) * inv2dy +
                            w_c * (w_zp - w_zm) * inv2dz;
        const float adv_T = u_c * (T_xp - T_xm) * inv2dx +
                            v_c * (T_yp - T_ym) * inv2dy +
                            w_c * (T_zp - T_zm) * inv2dz;

        du = (-dpdx + MUc * lap_u) * inv_r - adv_u;
        dv = (-dpdy + MUc * lap_v) * inv_r - adv_v;
        dw = (-Gc * r_c - dpdz + MUc * lap_w) * inv_r - adv_w;
        dT = (KTHc * lap_T) * inv_r * (1.0f / CVc) - adv_T;
    }

    o[b]          = du;
    o[b + FS]     = dv;
    o[b + 2 * FS] = dw;
    o[b + 3 * FS] = drou;
    o[b + 4 * FS] = dT;
    o[b + 5 * FS] = dc;
}

extern "C" void kernel_launch(void* const* d_in, const int* in_sizes, int n_in,
                              void* d_out, int out_size, void* d_ws, size_t ws_size,
                              hipStream_t stream) {
    (void)in_sizes; (void)n_in; (void)d_ws; (void)ws_size; (void)out_size;
    const float* s = (const float*)d_in[0];
    float* o = (float*)d_out;

    dim3 block(128, 2, 1);        // z fast (coalesced), 2 y rows per block
    dim3 grid(NYc / 2, NXc, 1);   // (y tiles, x)
    rb_kernel<<<grid, block, 0, stream>>>(s, o);
}

// Round 3
// 350.069 us; speedup vs baseline: 1.0681x; 1.0681x over previous
//
#include <hip/hip_runtime.h>

// Rayleigh-Benard tendency kernel, fp32 I/O, fp32 math.
// Layout: state[6][NX][NY][NZ], z contiguous.
// Each thread handles 4 consecutive z via float4; z-neighbors via wave shuffles.

namespace {
constexpr int NXc = 256, NYc = 256, NZc = 128;
constexpr int FS = NXc * NYc * NZc;   // field stride (elements)
constexpr int XS = NYc * NZc;         // x stride
constexpr int YS = NZc;               // y stride

constexpr float MUc = 1.8e-5f, KTHc = 0.025f, Gc = 9.8f;
constexpr float Rgas = 287.0f;        // CP - CV
constexpr float invCV = 1.0f / 717.0f;

// DX=1/256, DY=1/256, DZ=1/127 — exact in fp32
constexpr float inv2dx = 128.0f, inv2dy = 128.0f, inv2dz = 63.5f;
constexpr float invdx2 = 65536.0f, invdy2 = 65536.0f, invdz2 = 16129.0f;
}

__device__ __forceinline__ float4 ld4(const float* __restrict__ p, int i4) {
    return reinterpret_cast<const float4*>(p)[i4];
}

// Loads 4 neighbor float4s for field q and fetches z-halo scalars via shuffle.
#define LOADN(q, sq) \
    const float4 q##_xm = ld4(sq, bxm4), q##_xp = ld4(sq, bxp4); \
    const float4 q##_ym = ld4(sq, bym4), q##_yp = ld4(sq, byp4); \
    const float q##_zm = __shfl_up(q##_c.w, 1, 32); \
    const float q##_zp = __shfl_down(q##_c.x, 1, 32);

// Advection + Laplacian for one component C with z-neighbors PREV/NEXT.
#define ADV_LAP_C(q, C, PREV, NEXT) \
    adv_##q.C = u_c.C * (q##_xp.C - q##_xm.C) * inv2dx \
              + v_c.C * (q##_yp.C - q##_ym.C) * inv2dy \
              + w_c.C * ((NEXT) - (PREV)) * inv2dz; \
    lap_##q.C = (q##_xp.C + q##_xm.C - 2.0f * q##_c.C) * invdx2 \
              + (q##_yp.C + q##_ym.C - 2.0f * q##_c.C) * invdy2 \
              + ((NEXT) + (PREV) - 2.0f * q##_c.C) * invdz2;

#define DERIVS(q) \
    float4 adv_##q, lap_##q; \
    ADV_LAP_C(q, x, q##_zm,  q##_c.y) \
    ADV_LAP_C(q, y, q##_c.x, q##_c.z) \
    ADV_LAP_C(q, z, q##_c.y, q##_c.w) \
    ADV_LAP_C(q, w, q##_c.z, q##_zp)

__global__ __launch_bounds__(256) void rb_kernel(const float* __restrict__ s,
                                                 float* __restrict__ o) {
    const int l = threadIdx.x;                    // z-quad index 0..31 (lanes)
    const int y = blockIdx.x * 8 + threadIdx.y;   // 0..255
    const int x = blockIdx.y;                     // 0..255

    const int xm = (x == 0) ? NXc - 1 : x - 1;
    const int xp = (x == NXc - 1) ? 0 : x + 1;
    const int ym = (y == 0) ? NYc - 1 : y - 1;
    const int yp = (y == NYc - 1) ? 0 : y + 1;

    const int b4   = (x * XS + y * YS) / 4 + l;
    const int bxm4 = (xm * XS + y * YS) / 4 + l;
    const int bxp4 = (xp * XS + y * YS) / 4 + l;
    const int bym4 = (x * XS + ym * YS) / 4 + l;
    const int byp4 = (x * XS + yp * YS) / 4 + l;

    const float* su = s;
    const float* sv = s + FS;
    const float* sw = s + 2 * FS;
    const float* sr = s + 3 * FS;
    const float* st = s + 4 * FS;
    const float* sc = s + 5 * FS;

    const float4 u_c = ld4(su, b4), v_c = ld4(sv, b4), w_c = ld4(sw, b4);
    const float4 r_c = ld4(sr, b4), T_c = ld4(st, b4), c_c = ld4(sc, b4);

    float4 inv_r;
    inv_r.x = 1.0f / r_c.x; inv_r.y = 1.0f / r_c.y;
    inv_r.z = 1.0f / r_c.z; inv_r.w = 1.0f / r_c.w;

    // ---- T (stencil) and pressure gradients ----
    LOADN(T, st)
    DERIVS(T)
    LOADN(r, sr)

    float4 p_c, p_xm, p_xp, p_ym, p_yp;
#define PC(C) \
    p_c.C  = Rgas * r_c.C  * T_c.C; \
    p_xm.C = Rgas * r_xm.C * T_xm.C;  p_xp.C = Rgas * r_xp.C * T_xp.C; \
    p_ym.C = Rgas * r_ym.C * T_ym.C;  p_yp.C = Rgas * r_yp.C * T_yp.C;
    PC(x) PC(y) PC(z) PC(w)
#undef PC
    const float p_zm = __shfl_up(p_c.w, 1, 32);
    const float p_zp = __shfl_down(p_c.x, 1, 32);

    float4 dpdx, dpdy, dpdz;
#define DP(C) \
    dpdx.C = (p_xp.C - p_xm.C) * inv2dx; \
    dpdy.C = (p_yp.C - p_ym.C) * inv2dy;
    DP(x) DP(y) DP(z) DP(w)
#undef DP
    dpdz.x = (p_c.y - p_zm) * inv2dz;
    dpdz.y = (p_c.z - p_c.x) * inv2dz;
    dpdz.z = (p_c.w - p_c.y) * inv2dz;
    dpdz.w = (p_zp  - p_c.z) * inv2dz;

    // ---- u (+ drou, which needs r_x* and u_x*) ----
    LOADN(u, su)
    DERIVS(u)
    float4 drou;
#define DR(C) drou.C = -(r_xp.C * u_xp.C - r_xm.C * u_xm.C) * inv2dx;
    DR(x) DR(y) DR(z) DR(w)
#undef DR

    // ---- v ----
    LOADN(v, sv)
    DERIVS(v)

    // ---- w ----
    LOADN(w, sw)
    DERIVS(w)

    // ---- c (advection only; lap_c is dead code, DCE'd) ----
    LOADN(c, sc)
    DERIVS(c)
    (void)lap_c;

    float4 du4, dv4, dw4, dT4, dc4;
#define OUT(C) \
    du4.C = (-dpdx.C + MUc * lap_u.C) * inv_r.C - adv_u.C; \
    dv4.C = (-dpdy.C + MUc * lap_v.C) * inv_r.C - adv_v.C; \
    dw4.C = (-Gc * r_c.C - dpdz.C + MUc * lap_w.C) * inv_r.C - adv_w.C; \
    dT4.C = KTHc * lap_T.C * inv_r.C * invCV - adv_T.C; \
    dc4.C = -adv_c.C;
    OUT(x) OUT(y) OUT(z) OUT(w)
#undef OUT

    // z-wall fixes: lane 0 comp .x is z=0, lane 31 comp .w is z=127
    if (l == 0) {
        du4.x = 0.0f; dv4.x = 0.0f; dw4.x = 0.0f; dT4.x = 0.0f;
        const float dzc0 = (-3.0f * c_c.x + 4.0f * c_c.y - c_c.z) * inv2dz;
        dc4.x = -(u_c.x * (c_xp.x - c_xm.x) * inv2dx
                + v_c.x * (c_yp.x - c_ym.x) * inv2dy
                + w_c.x * dzc0);
    }
    if (l == 31) {
        du4.w = 0.0f; dv4.w = 0.0f; dw4.w = 0.0f; dT4.w = 0.0f;
        const float dzcN = (3.0f * c_c.w - 4.0f * c_c.z + c_c.y) * inv2dz;
        dc4.w = -(u_c.w * (c_xp.w - c_xm.w) * inv2dx
                + v_c.w * (c_yp.w - c_ym.w) * inv2dy
                + w_c.w * dzcN);
    }

    float4* o4 = reinterpret_cast<float4*>(o);
    const int fs4 = FS / 4;
    o4[b4]           = du4;
    o4[b4 + fs4]     = dv4;
    o4[b4 + 2 * fs4] = dw4;
    o4[b4 + 3 * fs4] = drou;
    o4[b4 + 4 * fs4] = dT4;
    o4[b4 + 5 * fs4] = dc4;
}

extern "C" void kernel_launch(void* const* d_in, const int* in_sizes, int n_in,
                              void* d_out, int out_size, void* d_ws, size_t ws_size,
                              hipStream_t stream) {
    (void)in_sizes; (void)n_in; (void)d_ws; (void)ws_size; (void)out_size;
    const float* s = (const float*)d_in[0];
    float* o = (float*)d_out;

    dim3 block(32, 8, 1);         // 32 z-quads (lanes) x 8 y rows = 256 threads
    dim3 grid(NYc / 8, NXc, 1);   // (y tiles, x)
    rb_kernel<<<grid, block, 0, stream>>>(s, o);
}